// Round 6
// baseline (100.972 us; speedup 1.0000x reference)
//
#include <hip/hip_runtime.h>
#include <math.h>

#define H     100
#define KPAD  112             // K padded to 7*16 for 32x32x16 MFMA
#define KC8   (KPAD / 8)      // 14 bf16x8 chunks per row
#define P     20
#define NCHW  21              // 20 weighted channels + 1 plain (cos)
#define SLEN  256
#define NB    8
#define NT    (NB * SLEN)     // 2048
#define NCH   105
#define SG    16              // rows per prep block
#define EPSV  1e-8f
#define NEGINF (-3.402823466e38f)

typedef __attribute__((ext_vector_type(8)))  short bf16x8;
typedef __attribute__((ext_vector_type(16))) float f32x16;

static __device__ __forceinline__ unsigned short f2bf(float f) {
    unsigned u = __builtin_bit_cast(unsigned, f);
    u = u + 0x7FFFu + ((u >> 16) & 1u);        // round-to-nearest-even
    return (unsigned short)(u >> 16);
}

// ---------------------------------------------------------------------------
// K1: norms (LDS-only) -> PRE-SCALED K-major bf16 panels.
//   A_sc[(b*21+ch)*14+kc][s] = bf16( w_mp[ch]^2 * c1[b,s] * r1[s,ch] )   (ch=20: c1*r)
//   B_sc[(b*21+ch)*14+kc][t] = bf16( c2[b,t] * r2[t,ch] )               (symmetric)
// MFMA of A_sc x B_sc then yields the final cosine/mv value directly.
// block = (ctx, b, s-group of 16). Norms never touch global.
// ---------------------------------------------------------------------------
__global__ __launch_bounds__(256) void prep_sc(
    const float* __restrict__ c1, const float* __restrict__ c2,
    const float* __restrict__ w_mp,
    unsigned short* __restrict__ Apb, unsigned short* __restrict__ Bpb) {

    __shared__ float rloc[SG][NCHW];
    const int blk = blockIdx.x;
    const int ctx = blk >> 7;
    const int b   = (blk >> 4) & 7;
    const int sg  = blk & 15;
    const int tid = threadIdx.x;
    const float* src = ctx ? c2 : c1;
    unsigned short* panel = ctx ? Bpb : Apb;
    const int row0 = b * SLEN + sg * SG;

    for (int j = tid; j < SG * NCHW; j += 256) {
        int rl = j / NCHW, chh = j - rl * NCHW;
        const float* v = src + (size_t)(row0 + rl) * H;
        float acc = 0.f;
        if (chh == P) {
            for (int h = 0; h < H; ++h) { float x = v[h]; acc = fmaf(x, x, acc); }
            rloc[rl][chh] = 1.f / fmaxf(sqrtf(acc), EPSV);
        } else {
            const float* wr = w_mp + chh * H;
            for (int h = 0; h < H; ++h) { float x = wr[h] * v[h]; acc = fmaf(x, x, acc); }
            rloc[rl][chh] = 1.f / fmaxf(sqrtf(acc), 1e-30f);
        }
    }
    __syncthreads();

    // SG*21*14 = 4704 pack jobs; row-fastest for coalesced 16B stores
    for (int j = tid; j < SG * NCHW * KC8; j += 256) {
        int rl  = j & (SG - 1);
        int kc  = (j >> 4) % KC8;
        int chh = (j >> 4) / KC8;
        const float* row = src + (size_t)(row0 + rl) * H;
        const float s = rloc[rl][chh];
        float xs[8];
#pragma unroll
        for (int e = 0; e < 8; ++e) xs[e] = 0.f;
        if (kc < 12) {
            float4 a0 = *reinterpret_cast<const float4*>(row + kc * 8);
            float4 a1 = *reinterpret_cast<const float4*>(row + kc * 8 + 4);
            xs[0]=a0.x; xs[1]=a0.y; xs[2]=a0.z; xs[3]=a0.w;
            xs[4]=a1.x; xs[5]=a1.y; xs[6]=a1.z; xs[7]=a1.w;
        } else if (kc == 12) {
            float4 a0 = *reinterpret_cast<const float4*>(row + 96);
            xs[0]=a0.x; xs[1]=a0.y; xs[2]=a0.z; xs[3]=a0.w;
        }
        if (ctx == 0 && chh < P) {       // A side carries the w^2 factor
            const float* wr = w_mp + chh * H;
            if (kc < 12) {
                float4 w0 = *reinterpret_cast<const float4*>(wr + kc * 8);
                float4 w1 = *reinterpret_cast<const float4*>(wr + kc * 8 + 4);
                xs[0]*=w0.x*w0.x; xs[1]*=w0.y*w0.y; xs[2]*=w0.z*w0.z; xs[3]*=w0.w*w0.w;
                xs[4]*=w1.x*w1.x; xs[5]*=w1.y*w1.y; xs[6]*=w1.z*w1.z; xs[7]*=w1.w*w1.w;
            } else if (kc == 12) {
                float4 w0 = *reinterpret_cast<const float4*>(wr + 96);
                xs[0]*=w0.x*w0.x; xs[1]*=w0.y*w0.y; xs[2]*=w0.z*w0.z; xs[3]*=w0.w*w0.w;
            }
        }
#pragma unroll
        for (int e = 0; e < 8; ++e) xs[e] *= s;
        uint4 pk;
        pk.x = (unsigned)f2bf(xs[0]) | ((unsigned)f2bf(xs[1]) << 16);
        pk.y = (unsigned)f2bf(xs[2]) | ((unsigned)f2bf(xs[3]) << 16);
        pk.z = (unsigned)f2bf(xs[4]) | ((unsigned)f2bf(xs[5]) << 16);
        pk.w = (unsigned)f2bf(xs[6]) | ((unsigned)f2bf(xs[7]) << 16);
        *reinterpret_cast<uint4*>(
            panel + ((size_t)((b * NCHW + chh) * KC8 + kc) * SLEN + sg * SG + rl) * 8) = pk;
    }
}

// ---------------------------------------------------------------------------
// K2: both-orientation MFMA GEMM, all stats in-register.
// block = (phase, b, ch); 4 waves; wave w owns output-cols c0=w*64+l31, c0+32.
//   phase 0 (normal):     C[s-row][t-col]  -> per-t over s in regs -> out2
//   phase 1 (transposed): C[t-row][s-col]  -> per-s over t in regs -> out1
// ch==20 & phase==0 additionally writes cosbuf (values are final cosines).
// Only cross-lane op: one shfl_xor(32) per stat at the very end.
// ---------------------------------------------------------------------------
__global__ __launch_bounds__(256) void gemm_all(
    const unsigned short* __restrict__ Apb, const unsigned short* __restrict__ Bpb,
    float* __restrict__ out, float* __restrict__ cosbuf) {

    const int blk   = blockIdx.x;
    const int phase = blk / (NB * NCHW);
    const int rem   = blk - phase * (NB * NCHW);
    const int ch    = rem % NCHW;
    const int b     = rem / NCHW;
    const int tid = threadIdx.x;
    const int w   = tid >> 6, l = tid & 63;
    const int l31 = l & 31,  lh = l >> 5;

    const bf16x8* PA = reinterpret_cast<const bf16x8*>(phase ? Bpb : Apb); // row operand
    const bf16x8* PB = reinterpret_cast<const bf16x8*>(phase ? Apb : Bpb); // col operand
    const long cb = (long)(b * NCHW + ch) * KC8;
    const int c0 = w * 64 + l31;

    bf16x8 colf[14];
#pragma unroll
    for (int k = 0; k < 7; ++k) {
        colf[2*k]   = PB[(cb + 2*k + lh) * SLEN + c0];
        colf[2*k+1] = PB[(cb + 2*k + lh) * SLEN + c0 + 32];
    }

    float mx0 = NEGINF, sm0 = 0.f, mx1 = NEGINF, sm1 = 0.f;
    const bool wcos = (ch == P) && (phase == 0);

    for (int rr = 0; rr < 8; ++rr) {
        f32x16 acc0, acc1;
#pragma unroll
        for (int i = 0; i < 16; ++i) { acc0[i] = 0.f; acc1[i] = 0.f; }
#pragma unroll
        for (int k = 0; k < 7; ++k) {
            bf16x8 af = PA[(cb + 2*k + lh) * SLEN + rr * 32 + l31];
            acc0 = __builtin_amdgcn_mfma_f32_32x32x16_bf16(af, colf[2*k],   acc0, 0, 0, 0);
            acc1 = __builtin_amdgcn_mfma_f32_32x32x16_bf16(af, colf[2*k+1], acc1, 0, 0, 0);
        }
#pragma unroll
        for (int r = 0; r < 16; ++r) {
            const float v0 = acc0[r], v1 = acc1[r];
            mx0 = fmaxf(mx0, v0); sm0 += v0;
            mx1 = fmaxf(mx1, v1); sm1 += v1;
            if (wcos) {
                const int row = rr * 32 + (r & 3) + 8 * (r >> 2) + 4 * lh;
                const long sg = (long)(b * SLEN + row) * SLEN;
                cosbuf[sg + c0]      = v0;
                cosbuf[sg + c0 + 32] = v1;
            }
        }
    }

    mx0 = fmaxf(mx0, __shfl_xor(mx0, 32)); sm0 += __shfl_xor(sm0, 32);
    mx1 = fmaxf(mx1, __shfl_xor(mx1, 32)); sm1 += __shfl_xor(sm1, 32);
    if (lh == 0) {
        float* obase = out + (phase ? 0 : (size_t)NT * NCH);   // phase0->out2, phase1->out1
        float* o0 = obase + (size_t)(b * SLEN + c0) * NCH;
        float* o1 = obase + (size_t)(b * SLEN + c0 + 32) * NCH;
        if (ch == P) {
            o0[0] = mx0; o0[1] = sm0 * (1.0f / SLEN);
            o1[0] = mx1; o1[1] = sm1 * (1.0f / SLEN);
        } else {
            o0[23 + ch] = mx0; o0[43 + ch] = sm0 * (1.0f / SLEN);
            o1[23 + ch] = mx1; o1[43 + ch] = sm1 * (1.0f / SLEN);
        }
    }
}

// ---------------------------------------------------------------------------
// K3: att num/max + FUSED finalize. Block = (dir, b, strip of 8 own-axis rows),
// 128 threads. Main loop as round 5; attnum/attmax stay in LDS; then the block
// finalizes its 8 tokens: channels 2..22 (w_full/last), 63..83 (w_att/att_mean
// numerator), 84..104 (w_maxatt/att_max).
// ---------------------------------------------------------------------------
__global__ __launch_bounds__(128) void att_fin(
    const float* __restrict__ c1, const float* __restrict__ c2,
    const float* __restrict__ cosbuf,
    const float* __restrict__ w_full, const float* __restrict__ w_att,
    const float* __restrict__ w_matt,
    float* __restrict__ out) {

    __shared__ float cosL[8][SLEN];
    __shared__ float Blds[32][104];
    __shared__ float anm[8][104], amx[8][104];
    __shared__ float blast[104];

    const int blk  = blockIdx.x;
    const int dir  = blk >> 8;
    const int rem  = blk & 255;
    const int b    = rem >> 5;
    const int strip = rem & 31;
    const int tid  = threadIdx.x;
    const float* Bsrc = dir ? c1 : c2;
    const float* Asrc = dir ? c2 : c1;
    float* outBase = out + (dir ? (size_t)NT * NCH : 0);
    const int row0 = b * SLEN + strip * 8;

    if (dir == 0) {          // cosL[sl][t] = cos[row0+sl][t]
        const float4* cb4 = reinterpret_cast<const float4*>(cosbuf);
        for (int i = tid; i < 8 * 64; i += 128) {
            int sl = i >> 6, tq = i & 63;
            reinterpret_cast<float4*>(&cosL[sl][0])[tq] = cb4[(long)(row0 + sl) * 64 + tq];
        }
    } else {                 // cosL[tl][s] = cos[s][strip*8+tl]  (transposed)
        for (int i = tid; i < 2048; i += 128) {
            int tl = i & 7, s = i >> 3;
            cosL[tl][s] = cosbuf[(long)(b * SLEN + s) * SLEN + strip * 8 + tl];
        }
    }
    if (tid < 25)            // B last row (len==256) for the w_full match
        reinterpret_cast<float4*>(blast)[tid] =
            *reinterpret_cast<const float4*>(&Bsrc[(size_t)(b * SLEN + (SLEN - 1)) * H + tid * 4]);

    const int sl = tid >> 5;          // 0..3 -> rows sl and sl+4
    const int hq = tid & 31;          // active < 25
    float4 num0 = {0.f,0.f,0.f,0.f}, num1 = {0.f,0.f,0.f,0.f};
    float4 mx0  = {NEGINF,NEGINF,NEGINF,NEGINF}, mx1 = {NEGINF,NEGINF,NEGINF,NEGINF};

    for (int tc = 0; tc < 8; ++tc) {
        __syncthreads();     // (iter 0: also publishes cosL + blast)
        for (int i = tid; i < 800; i += 128) {
            int r = i / 25, q = i - r * 25;
            *reinterpret_cast<float4*>(&Blds[r][q * 4]) =
                *reinterpret_cast<const float4*>(&Bsrc[(size_t)(b * SLEN + tc * 32 + r) * H + q * 4]);
        }
        __syncthreads();
        if (hq < 25) {
#pragma unroll
            for (int t4 = 0; t4 < 8; ++t4) {
                float4 c4a = *reinterpret_cast<const float4*>(&cosL[sl][tc * 32 + t4 * 4]);
                float4 c4b = *reinterpret_cast<const float4*>(&cosL[sl + 4][tc * 32 + t4 * 4]);
                float ca[4] = {c4a.x, c4a.y, c4a.z, c4a.w};
                float cb[4] = {c4b.x, c4b.y, c4b.z, c4b.w};
#pragma unroll
                for (int e = 0; e < 4; ++e) {
                    float4 bv = *reinterpret_cast<const float4*>(&Blds[t4 * 4 + e][hq * 4]);
                    float cva = ca[e], cvb = cb[e];
                    num0.x = fmaf(bv.x, cva, num0.x);  mx0.x = fmaxf(mx0.x, bv.x * cva);
                    num0.y = fmaf(bv.y, cva, num0.y);  mx0.y = fmaxf(mx0.y, bv.y * cva);
                    num0.z = fmaf(bv.z, cva, num0.z);  mx0.z = fmaxf(mx0.z, bv.z * cva);
                    num0.w = fmaf(bv.w, cva, num0.w);  mx0.w = fmaxf(mx0.w, bv.w * cva);
                    num1.x = fmaf(bv.x, cvb, num1.x);  mx1.x = fmaxf(mx1.x, bv.x * cvb);
                    num1.y = fmaf(bv.y, cvb, num1.y);  mx1.y = fmaxf(mx1.y, bv.y * cvb);
                    num1.z = fmaf(bv.z, cvb, num1.z);  mx1.z = fmaxf(mx1.z, bv.z * cvb);
                    num1.w = fmaf(bv.w, cvb, num1.w);  mx1.w = fmaxf(mx1.w, bv.w * cvb);
                }
            }
        }
    }
    if (hq < 25) {
        *reinterpret_cast<float4*>(&anm[sl][hq * 4])     = num0;
        *reinterpret_cast<float4*>(&amx[sl][hq * 4])     = mx0;
        *reinterpret_cast<float4*>(&anm[sl + 4][hq * 4]) = num1;
        *reinterpret_cast<float4*>(&amx[sl + 4][hq * 4]) = mx1;
    }
    __syncthreads();

    // ---- fused finalize: 8 tokens x 63 channels --------------------------
    for (int j = tid; j < 8 * 63; j += 128) {
        int tl = j / 63, rest = j - tl * 63;
        int m = rest / 21, k2 = rest - m * 21;
        const float* wm = (m == 0) ? w_full : (m == 1) ? w_att : w_matt;
        const float* v1 = Asrc + (size_t)(row0 + tl) * H;
        const float* v2 = (m == 0) ? blast : (m == 1) ? &anm[tl][0] : &amx[tl][0];
        float dot = 0.f, s1 = 0.f, s2 = 0.f;
        if (k2 < P) {
            const float* wr = wm + k2 * H;
            for (int h = 0; h < H; ++h) {
                float wv = wr[h], w2 = wv * wv;
                float x = v1[h], y = v2[h];
                dot = fmaf(w2 * x, y, dot);
                s1  = fmaf(w2 * x, x, s1);
                s2  = fmaf(w2 * y, y, s2);
            }
        } else {
            for (int h = 0; h < H; ++h) {
                float x = v1[h], y = v2[h];
                dot = fmaf(x, y, dot);
                s1  = fmaf(x, x, s1);
                s2  = fmaf(y, y, s2);
            }
        }
        float val = dot / (fmaxf(sqrtf(s1), EPSV) * fmaxf(sqrtf(s2), EPSV));
        int chn = (m == 0) ? (k2 < P ? 3 + k2 : 2)
                : (m == 1) ? (k2 < P ? 64 + k2 : 63)
                           : (k2 < P ? 85 + k2 : 84);
        outBase[(size_t)(row0 + tl) * NCH + chn] = val;
    }
}

// ---------------------------------------------------------------------------
extern "C" void kernel_launch(void* const* d_in, const int* in_sizes, int n_in,
                              void* d_out, int out_size, void* d_ws, size_t ws_size,
                              hipStream_t stream) {
    const float* c1     = (const float*)d_in[0];
    const float* c2     = (const float*)d_in[2];
    const float* w_full = (const float*)d_in[4];
    const float* w_mp   = (const float*)d_in[5];
    const float* w_att  = (const float*)d_in[6];
    const float* w_matt = (const float*)d_in[7];
    float* out = (float*)d_out;

    float* ws = (float*)d_ws;
    float* cosbuf = ws;                                      // NB*256*256
    unsigned short* Apb = (unsigned short*)(cosbuf + (size_t)NB * SLEN * SLEN);
    unsigned short* Bpb = Apb + (size_t)NB * NCHW * SLEN * KPAD;

    prep_sc<<<2 * NB * 16, 256, 0, stream>>>(c1, c2, w_mp, Apb, Bpb);

    gemm_all<<<2 * NB * NCHW, 256, 0, stream>>>(Apb, Bpb, out, cosbuf);

    att_fin<<<2 * NB * 32, 128, 0, stream>>>(c1, c2, cosbuf,
                                             w_full, w_att, w_matt, out);
}

// Round 7
// 84.076 us; speedup vs baseline: 1.2010x; 1.2010x over previous
//
#include <hip/hip_runtime.h>
#include <math.h>

#define H     100
#define KPAD  112             // K padded to 7*16 for 32x32x16 MFMA
#define KC8   (KPAD / 8)      // 14 bf16x8 chunks per row
#define P     20
#define NCHW  21              // 20 weighted channels + 1 plain (cos)
#define SLEN  256
#define NB    8
#define NT    (NB * SLEN)     // 2048
#define NCH   105
#define SG    4               // rows per prep block
#define EPSV  1e-8f
#define NEGINF (-3.402823466e38f)

typedef __attribute__((ext_vector_type(8)))  short bf16x8;
typedef __attribute__((ext_vector_type(16))) float f32x16;

static __device__ __forceinline__ unsigned short f2bf(float f) {
    unsigned u = __builtin_bit_cast(unsigned, f);
    u = u + 0x7FFFu + ((u >> 16) & 1u);        // round-to-nearest-even
    return (unsigned short)(u >> 16);
}

// ---------------------------------------------------------------------------
// K1: norms (LDS-only) -> PRE-SCALED K-major bf16 panels.
//   A_sc[(b*21+ch)*14+kc][s] = bf16( w_mp[ch]^2 * c1[b,s] * r1[s,ch] )  (ch=20: c1*r)
//   B_sc[(b*21+ch)*14+kc][t] = bf16( c2[b,t] * r2[t,ch] )
// block = (ctx, b, s-group of 4), 128 threads. grid 1024.
// ---------------------------------------------------------------------------
__global__ __launch_bounds__(128) void prep_sc(
    const float* __restrict__ c1, const float* __restrict__ c2,
    const float* __restrict__ w_mp,
    unsigned short* __restrict__ Apb, unsigned short* __restrict__ Bpb) {

    __shared__ float rloc[SG][NCHW];
    const int blk = blockIdx.x;
    const int ctx = blk >> 9;
    const int b   = (blk >> 6) & 7;
    const int sg  = blk & 63;
    const int tid = threadIdx.x;
    const float* src = ctx ? c2 : c1;
    unsigned short* panel = ctx ? Bpb : Apb;
    const int row0 = b * SLEN + sg * SG;

    if (tid < SG * NCHW) {                       // 84 norm jobs, vectorized
        int rl = tid / NCHW, chh = tid - rl * NCHW;
        const float* v = src + (size_t)(row0 + rl) * H;
        float acc = 0.f;
        if (chh == P) {
            for (int q = 0; q < 25; ++q) {
                float4 a = *reinterpret_cast<const float4*>(v + q * 4);
                acc = fmaf(a.x, a.x, fmaf(a.y, a.y, fmaf(a.z, a.z, fmaf(a.w, a.w, acc))));
            }
            rloc[rl][chh] = 1.f / fmaxf(sqrtf(acc), EPSV);
        } else {
            const float* wr = w_mp + chh * H;
            for (int q = 0; q < 25; ++q) {
                float4 a = *reinterpret_cast<const float4*>(v + q * 4);
                float4 w = *reinterpret_cast<const float4*>(wr + q * 4);
                float x0 = a.x * w.x, x1 = a.y * w.y, x2 = a.z * w.z, x3 = a.w * w.w;
                acc = fmaf(x0, x0, fmaf(x1, x1, fmaf(x2, x2, fmaf(x3, x3, acc))));
            }
            rloc[rl][chh] = 1.f / fmaxf(sqrtf(acc), 1e-30f);
        }
    }
    __syncthreads();

    // SG*21*14 = 1176 pack jobs; row-fastest for coalesced 16B stores
    for (int j = tid; j < SG * NCHW * KC8; j += 128) {
        int rl  = j & (SG - 1);
        int kc  = (j >> 2) % KC8;
        int chh = (j >> 2) / KC8;
        const float* row = src + (size_t)(row0 + rl) * H;
        const float s = rloc[rl][chh];
        float xs[8];
#pragma unroll
        for (int e = 0; e < 8; ++e) xs[e] = 0.f;
        if (kc < 12) {
            float4 a0 = *reinterpret_cast<const float4*>(row + kc * 8);
            float4 a1 = *reinterpret_cast<const float4*>(row + kc * 8 + 4);
            xs[0]=a0.x; xs[1]=a0.y; xs[2]=a0.z; xs[3]=a0.w;
            xs[4]=a1.x; xs[5]=a1.y; xs[6]=a1.z; xs[7]=a1.w;
        } else if (kc == 12) {
            float4 a0 = *reinterpret_cast<const float4*>(row + 96);
            xs[0]=a0.x; xs[1]=a0.y; xs[2]=a0.z; xs[3]=a0.w;
        }
        if (ctx == 0 && chh < P) {       // A side carries the w^2 factor
            const float* wr = w_mp + chh * H;
            if (kc < 12) {
                float4 w0 = *reinterpret_cast<const float4*>(wr + kc * 8);
                float4 w1 = *reinterpret_cast<const float4*>(wr + kc * 8 + 4);
                xs[0]*=w0.x*w0.x; xs[1]*=w0.y*w0.y; xs[2]*=w0.z*w0.z; xs[3]*=w0.w*w0.w;
                xs[4]*=w1.x*w1.x; xs[5]*=w1.y*w1.y; xs[6]*=w1.z*w1.z; xs[7]*=w1.w*w1.w;
            } else if (kc == 12) {
                float4 w0 = *reinterpret_cast<const float4*>(wr + 96);
                xs[0]*=w0.x*w0.x; xs[1]*=w0.y*w0.y; xs[2]*=w0.z*w0.z; xs[3]*=w0.w*w0.w;
            }
        }
#pragma unroll
        for (int e = 0; e < 8; ++e) xs[e] *= s;
        uint4 pk;
        pk.x = (unsigned)f2bf(xs[0]) | ((unsigned)f2bf(xs[1]) << 16);
        pk.y = (unsigned)f2bf(xs[2]) | ((unsigned)f2bf(xs[3]) << 16);
        pk.z = (unsigned)f2bf(xs[4]) | ((unsigned)f2bf(xs[5]) << 16);
        pk.w = (unsigned)f2bf(xs[6]) | ((unsigned)f2bf(xs[7]) << 16);
        *reinterpret_cast<uint4*>(
            panel + ((size_t)((b * NCHW + chh) * KC8 + kc) * SLEN + sg * SG + rl) * 8) = pk;
    }
}

// ---------------------------------------------------------------------------
// K2: both-orientation MFMA GEMM, stats in-register. block = (phase,b,ch,cg);
// 4 waves x 1 col-tile (32 cols) each; cg picks which half of 8 tiles.
//   phase 0: C[s][t] -> per-t stats -> out2;  phase 1: C[t][s] -> out1
// ch==20 & phase==0 writes cosbuf (values are final cosines).
// ---------------------------------------------------------------------------
__global__ __launch_bounds__(256) void gemm_all(
    const unsigned short* __restrict__ Apb, const unsigned short* __restrict__ Bpb,
    float* __restrict__ out, float* __restrict__ cosbuf) {

    int t = blockIdx.x;
    const int cg = t & 1;  t >>= 1;
    const int ch = t % NCHW; t /= NCHW;
    const int b  = t & 7;
    const int phase = t >> 3;
    const int tid = threadIdx.x;
    const int w   = tid >> 6, l = tid & 63;
    const int l31 = l & 31,  lh = l >> 5;

    const bf16x8* PA = reinterpret_cast<const bf16x8*>(phase ? Bpb : Apb); // row operand
    const bf16x8* PB = reinterpret_cast<const bf16x8*>(phase ? Apb : Bpb); // col operand
    const long cb = (long)(b * NCHW + ch) * KC8;
    const int c0 = (cg * 4 + w) * 32 + l31;

    bf16x8 colf[7];
#pragma unroll
    for (int k = 0; k < 7; ++k)
        colf[k] = PB[(cb + 2 * k + lh) * SLEN + c0];

    float mx = NEGINF, sm = 0.f;
    const bool wcos = (ch == P) && (phase == 0);

    for (int rr = 0; rr < 8; ++rr) {
        f32x16 acc;
#pragma unroll
        for (int i = 0; i < 16; ++i) acc[i] = 0.f;
#pragma unroll
        for (int k = 0; k < 7; ++k) {
            bf16x8 af = PA[(cb + 2 * k + lh) * SLEN + rr * 32 + l31];
            acc = __builtin_amdgcn_mfma_f32_32x32x16_bf16(af, colf[k], acc, 0, 0, 0);
        }
#pragma unroll
        for (int r = 0; r < 16; ++r) {
            const float v = acc[r];
            mx = fmaxf(mx, v); sm += v;
            if (wcos) {
                const int row = rr * 32 + (r & 3) + 8 * (r >> 2) + 4 * lh;
                cosbuf[(long)(b * SLEN + row) * SLEN + c0] = v;
            }
        }
    }

    mx = fmaxf(mx, __shfl_xor(mx, 32)); sm += __shfl_xor(sm, 32);
    if (lh == 0) {
        float* obase = out + (phase ? 0 : (size_t)NT * NCH);   // phase0->out2, phase1->out1
        float* o0 = obase + (size_t)(b * SLEN + c0) * NCH;
        if (ch == P) { o0[0] = mx; o0[1] = sm * (1.0f / SLEN); }
        else         { o0[23 + ch] = mx; o0[43 + ch] = sm * (1.0f / SLEN); }
    }
}

// ---------------------------------------------------------------------------
// K3a: att partials. block = (dir, b, strip of 8 own-axis rows, t-chunk of 64).
// grid 2048, 128 threads (sl 0..3 x hq 0..31; each thread rows sl, sl+4).
// pnum/pmax[((dir*NT+tok)*4 + tch)*100 + h]
// ---------------------------------------------------------------------------
__global__ __launch_bounds__(128) void att_part(
    const float* __restrict__ c1, const float* __restrict__ c2,
    const float* __restrict__ cosbuf,
    float* __restrict__ pnum, float* __restrict__ pmax) {

    __shared__ __attribute__((aligned(16))) float cosL[8][64];
    __shared__ __attribute__((aligned(16))) float Blds[32][104];

    const int blk  = blockIdx.x;
    const int tch  = blk & 3;
    const int strip = (blk >> 2) & 31;
    const int b    = (blk >> 7) & 7;
    const int dir  = blk >> 10;
    const int tid  = threadIdx.x;
    const float* Bsrc = dir ? c1 : c2;
    const int row0 = b * SLEN + strip * 8;

    if (dir == 0) {          // cosL[sl][tl] = cos[row0+sl][tch*64+tl]
        for (int i = tid; i < 8 * 16; i += 128) {
            int sl = i >> 4, tq = i & 15;
            reinterpret_cast<float4*>(&cosL[sl][0])[tq] =
                reinterpret_cast<const float4*>(cosbuf + (long)(row0 + sl) * SLEN + tch * 64)[tq];
        }
    } else {                 // cosL[tl][s'] = cos[tch*64+s'][strip*8+tl]
        for (int i = tid; i < 512; i += 128) {
            int tl = i & 7, s = i >> 3;
            cosL[tl][s] = cosbuf[(long)(b * SLEN + tch * 64 + s) * SLEN + strip * 8 + tl];
        }
    }

    const int sl = tid >> 5;          // 0..3 -> rows sl and sl+4
    const int hq = tid & 31;          // active < 25
    float4 num0 = {0.f,0.f,0.f,0.f}, num1 = {0.f,0.f,0.f,0.f};
    float4 mx0  = {NEGINF,NEGINF,NEGINF,NEGINF}, mx1 = {NEGINF,NEGINF,NEGINF,NEGINF};

    for (int tc = 0; tc < 2; ++tc) {
        __syncthreads();     // (iter 0: also publishes cosL)
        for (int i = tid; i < 800; i += 128) {
            int r = i / 25, q = i - r * 25;
            *reinterpret_cast<float4*>(&Blds[r][q * 4]) =
                *reinterpret_cast<const float4*>(
                    &Bsrc[(size_t)(b * SLEN + tch * 64 + tc * 32 + r) * H + q * 4]);
        }
        __syncthreads();
        if (hq < 25) {
#pragma unroll
            for (int t4 = 0; t4 < 8; ++t4) {
                float4 c4a = *reinterpret_cast<const float4*>(&cosL[sl][tc * 32 + t4 * 4]);
                float4 c4b = *reinterpret_cast<const float4*>(&cosL[sl + 4][tc * 32 + t4 * 4]);
                float ca[4] = {c4a.x, c4a.y, c4a.z, c4a.w};
                float cb[4] = {c4b.x, c4b.y, c4b.z, c4b.w};
#pragma unroll
                for (int e = 0; e < 4; ++e) {
                    float4 bv = *reinterpret_cast<const float4*>(&Blds[t4 * 4 + e][hq * 4]);
                    float cva = ca[e], cvb = cb[e];
                    num0.x = fmaf(bv.x, cva, num0.x);  mx0.x = fmaxf(mx0.x, bv.x * cva);
                    num0.y = fmaf(bv.y, cva, num0.y);  mx0.y = fmaxf(mx0.y, bv.y * cva);
                    num0.z = fmaf(bv.z, cva, num0.z);  mx0.z = fmaxf(mx0.z, bv.z * cva);
                    num0.w = fmaf(bv.w, cva, num0.w);  mx0.w = fmaxf(mx0.w, bv.w * cva);
                    num1.x = fmaf(bv.x, cvb, num1.x);  mx1.x = fmaxf(mx1.x, bv.x * cvb);
                    num1.y = fmaf(bv.y, cvb, num1.y);  mx1.y = fmaxf(mx1.y, bv.y * cvb);
                    num1.z = fmaf(bv.z, cvb, num1.z);  mx1.z = fmaxf(mx1.z, bv.z * cvb);
                    num1.w = fmaf(bv.w, cvb, num1.w);  mx1.w = fmaxf(mx1.w, bv.w * cvb);
                }
            }
        }
    }
    if (hq < 25) {
        const long o0 = ((long)(dir * NT + row0 + sl) * 4 + tch) * 100 + hq * 4;
        const long o1 = ((long)(dir * NT + row0 + sl + 4) * 4 + tch) * 100 + hq * 4;
        *reinterpret_cast<float4*>(pnum + o0) = num0;
        *reinterpret_cast<float4*>(pmax + o0) = mx0;
        *reinterpret_cast<float4*>(pnum + o1) = num1;
        *reinterpret_cast<float4*>(pmax + o1) = mx1;
    }
}

// ---------------------------------------------------------------------------
// K3b: combine partials + fused finalize. block = (dir, b, strip of 8), 128 thr.
// ---------------------------------------------------------------------------
__global__ __launch_bounds__(128) void att_fin2(
    const float* __restrict__ c1, const float* __restrict__ c2,
    const float* __restrict__ pnum, const float* __restrict__ pmax,
    const float* __restrict__ w_full, const float* __restrict__ w_att,
    const float* __restrict__ w_matt,
    float* __restrict__ out) {

    __shared__ __attribute__((aligned(16))) float anm[8][100], amx[8][100], blast[100];

    const int blk  = blockIdx.x;
    const int dir  = blk >> 8;
    const int rem  = blk & 255;
    const int b    = rem >> 5;
    const int strip = rem & 31;
    const int tid  = threadIdx.x;
    const float* Bsrc = dir ? c1 : c2;
    const float* Asrc = dir ? c2 : c1;
    float* outBase = out + (dir ? (size_t)NT * NCH : 0);
    const int row0 = b * SLEN + strip * 8;

    if (tid < 25)
        reinterpret_cast<float4*>(blast)[tid] =
            *reinterpret_cast<const float4*>(&Bsrc[(size_t)(b * SLEN + (SLEN - 1)) * H + tid * 4]);

    for (int j = tid; j < 200; j += 128) {       // 8 rows x 25 quads
        int rl = j / 25, q = j - rl * 25;
        const long base = ((long)(dir * NT + row0 + rl) * 4) * 100 + q * 4;
        float4 n = *reinterpret_cast<const float4*>(pnum + base);
        float4 m = *reinterpret_cast<const float4*>(pmax + base);
#pragma unroll
        for (int cch = 1; cch < 4; ++cch) {
            float4 n2 = *reinterpret_cast<const float4*>(pnum + base + cch * 100);
            float4 m2 = *reinterpret_cast<const float4*>(pmax + base + cch * 100);
            n.x += n2.x; n.y += n2.y; n.z += n2.z; n.w += n2.w;
            m.x = fmaxf(m.x, m2.x); m.y = fmaxf(m.y, m2.y);
            m.z = fmaxf(m.z, m2.z); m.w = fmaxf(m.w, m2.w);
        }
        *reinterpret_cast<float4*>(&anm[rl][q * 4]) = n;
        *reinterpret_cast<float4*>(&amx[rl][q * 4]) = m;
    }
    __syncthreads();

    // ---- fused finalize: 8 tokens x 63 channels --------------------------
    for (int j = tid; j < 8 * 63; j += 128) {
        int tl = j / 63, rest = j - tl * 63;
        int m = rest / 21, k2 = rest - m * 21;
        const float* wm = (m == 0) ? w_full : (m == 1) ? w_att : w_matt;
        const float* v1 = Asrc + (size_t)(row0 + tl) * H;
        const float* v2 = (m == 0) ? blast : (m == 1) ? &anm[tl][0] : &amx[tl][0];
        float dot = 0.f, s1 = 0.f, s2 = 0.f;
        if (k2 < P) {
            const float* wr = wm + k2 * H;
            for (int h = 0; h < H; ++h) {
                float wv = wr[h], w2 = wv * wv;
                float x = v1[h], y = v2[h];
                dot = fmaf(w2 * x, y, dot);
                s1  = fmaf(w2 * x, x, s1);
                s2  = fmaf(w2 * y, y, s2);
            }
        } else {
            for (int h = 0; h < H; ++h) {
                float x = v1[h], y = v2[h];
                dot = fmaf(x, y, dot);
                s1  = fmaf(x, x, s1);
                s2  = fmaf(y, y, s2);
            }
        }
        float val = dot / (fmaxf(sqrtf(s1), EPSV) * fmaxf(sqrtf(s2), EPSV));
        int chn = (m == 0) ? (k2 < P ? 3 + k2 : 2)
                : (m == 1) ? (k2 < P ? 64 + k2 : 63)
                           : (k2 < P ? 85 + k2 : 84);
        outBase[(size_t)(row0 + tl) * NCH + chn] = val;
    }
}

// ---------------------------------------------------------------------------
extern "C" void kernel_launch(void* const* d_in, const int* in_sizes, int n_in,
                              void* d_out, int out_size, void* d_ws, size_t ws_size,
                              hipStream_t stream) {
    const float* c1     = (const float*)d_in[0];
    const float* c2     = (const float*)d_in[2];
    const float* w_full = (const float*)d_in[4];
    const float* w_mp   = (const float*)d_in[5];
    const float* w_att  = (const float*)d_in[6];
    const float* w_matt = (const float*)d_in[7];
    float* out = (float*)d_out;

    float* ws = (float*)d_ws;
    float* cosbuf = ws;                                      // NB*256*256
    unsigned short* Apb = (unsigned short*)(cosbuf + (size_t)NB * SLEN * SLEN);
    unsigned short* Bpb = Apb + (size_t)NB * NCHW * SLEN * KPAD;
    // partials alias the panels (dead after gemm_all): 6.55 MB <= 9.63 MB each
    float* pnum = (float*)Apb;
    float* pmax = (float*)Bpb;

    prep_sc<<<2 * NB * 64, 128, 0, stream>>>(c1, c2, w_mp, Apb, Bpb);

    gemm_all<<<2 * NB * NCHW * 2, 256, 0, stream>>>(Apb, Bpb, out, cosbuf);

    att_part<<<2 * NB * 32 * 4, 128, 0, stream>>>(c1, c2, cosbuf, pnum, pmax);

    att_fin2<<<2 * NB * 32, 128, 0, stream>>>(c1, c2, pnum, pmax,
                                              w_full, w_att, w_matt, out);
}